// Round 1
// baseline (1792.431 us; speedup 1.0000x reference)
//
#include <hip/hip_runtime.h>

// Problem constants
#define K_CODES 1024
#define C_DIM   256
#define HWN     1024      // H*W
#define N_TOT   32768     // B*H*W
#define NELEM   8388608   // B*C*H*W
#define BIGF    3.4e38f

// ---------------- ws layout (in floats) ----------------
// dw        : [0,       262144)
// counts    : [262144,  263168)
// loss_acc  : [263168,  263169)   -- memset range ends here
// pmin      : [263424,  +65536)
// pidx(int) : [328960,  +65536)
// enorm     : [394496,  +1024)
// csize     : [395520,  +1024)

// ---------------- d_out layout (floats) ----------------
// q_out     : 0          (8388608)
// loss      : 8388608
// perplexity: 8388609
// token_map : 8388610    (32768, as float)
// new_cs    : 8421378    (1024)
// new_ema_w : 8422402    (262144)
// new_emb   : 8684546    (262144)

__global__ void vq_enorm(const float* __restrict__ e, float* __restrict__ enorm) {
    const int t = threadIdx.x;
    const int w = t >> 6;          // wave in block (0..3)
    const int lane = t & 63;
    const int k = blockIdx.x * 4 + w;
    const float4 v = *(const float4*)(e + (size_t)k * C_DIM + lane * 4);
    float s = fmaf(v.x, v.x, fmaf(v.y, v.y, fmaf(v.z, v.z, v.w * v.w)));
    #pragma unroll
    for (int off = 32; off > 0; off >>= 1) s += __shfl_down(s, off, 64);
    if (lane == 0) enorm[k] = s;
}

// Fused distance-GEMM + argmin.
// grid (256 n-tiles, 2 k-halves), block 256.
// Tile: 128 n-rows x 512 k-range (4 subtiles of 128 k).
// Thread (ty,tx): 8 rows (ty*8+i), 8 cols (tx*8+j) per subtile.
__global__ __launch_bounds__(256, 2)
void vq_argmin(const float* __restrict__ z, const float* __restrict__ e,
               const float* __restrict__ enorm,
               float* __restrict__ pmin, int* __restrict__ pidx) {
    __shared__ float es[8][132];           // [c][k-phys], swizzled, 2-way banks max
    __shared__ float red_d[16][16][8];
    __shared__ int   red_i[16][16][8];

    const int tid = threadIdx.x;
    const int tx = tid & 15;
    const int ty = tid >> 4;
    const int n0 = blockIdx.x * 128;
    const int ksplit = blockIdx.y;
    const int b = n0 >> 10;
    const int p0 = n0 & 1023;
    // z_flat[n][c] = z[b*C*HW + c*HW + p]; rows of this tile share b.
    const float* zb = z + (size_t)b * (C_DIM * HWN) + p0;

    // e-staging: thread loads e[kb+kk][cb+c4..c4+3]
    const int kk = tid >> 1;
    const int c4 = (tid & 1) * 4;
    const int phys = kk ^ (((kk >> 5) & 3) << 2);   // XOR swizzle

    const int sw = ((tx >> 2) & 3) << 2;
    const int pA = (tx * 8) ^ sw;
    const int pB = (tx * 8 + 4) ^ sw;

    float bestd[8];
    int   besti[8];
    #pragma unroll
    for (int i = 0; i < 8; i++) { bestd[i] = BIGF; besti[i] = 0; }

    for (int ks = 0; ks < 4; ++ks) {
        const int kb = ksplit * 512 + ks * 128;
        float acc[8][8];
        #pragma unroll
        for (int i = 0; i < 8; i++)
            #pragma unroll
            for (int j = 0; j < 8; j++) acc[i][j] = 0.0f;

        for (int cb = 0; cb < C_DIM; cb += 8) {
            __syncthreads();
            const float4 ev = *(const float4*)(e + (size_t)(kb + kk) * C_DIM + cb + c4);
            es[c4 + 0][phys] = ev.x;
            es[c4 + 1][phys] = ev.y;
            es[c4 + 2][phys] = ev.z;
            es[c4 + 3][phys] = ev.w;
            __syncthreads();
            #pragma unroll
            for (int c = 0; c < 8; c++) {
                const float* zc = zb + (size_t)(cb + c) * HWN + ty * 8;
                const float4 z0 = *(const float4*)(zc);
                const float4 z1 = *(const float4*)(zc + 4);
                const float4 e0 = *(const float4*)&es[c][pA];
                const float4 e1 = *(const float4*)&es[c][pB];
                const float zr[8] = {z0.x, z0.y, z0.z, z0.w, z1.x, z1.y, z1.z, z1.w};
                const float er[8] = {e0.x, e0.y, e0.z, e0.w, e1.x, e1.y, e1.z, e1.w};
                #pragma unroll
                for (int i = 0; i < 8; i++)
                    #pragma unroll
                    for (int j = 0; j < 8; j++)
                        acc[i][j] = fmaf(zr[i], er[j], acc[i][j]);
            }
        }
        // d = ||e_k||^2 - 2 z.e ; running argmin, k ascending (ties -> lowest k)
        #pragma unroll
        for (int j = 0; j < 8; j++) {
            const int kidx = kb + tx * 8 + j;
            const float en = enorm[kidx];
            #pragma unroll
            for (int i = 0; i < 8; i++) {
                const float d = fmaf(-2.0f, acc[i][j], en);
                if (d < bestd[i]) { bestd[i] = d; besti[i] = kidx; }
            }
        }
    }

    __syncthreads();
    #pragma unroll
    for (int i = 0; i < 8; i++) { red_d[ty][tx][i] = bestd[i]; red_i[ty][tx][i] = besti[i]; }
    __syncthreads();
    if (tid < 128) {
        const int tyr = tid >> 3, ir = tid & 7;
        float bd = BIGF; int bi = 0;
        for (int t = 0; t < 16; t++) {            // tx ascending == k ascending
            const float d = red_d[tyr][t][ir];
            if (d < bd) { bd = d; bi = red_i[tyr][t][ir]; }
        }
        const int n = n0 + tid;                   // tyr*8+ir == tid
        pmin[(size_t)ksplit * N_TOT + n] = bd;
        pidx[(size_t)ksplit * N_TOT + n] = bi;
    }
}

// Combine k-halves, gather codes, write q/token_map, loss partial, counts, dw.
// grid 128 blocks x 256 threads; block owns 256 consecutive n (same b).
__global__ __launch_bounds__(256)
void vq_gather(const float* __restrict__ z, const float* __restrict__ e,
               const float* __restrict__ pmin, const int* __restrict__ pidx,
               float* __restrict__ counts, float* __restrict__ dw,
               float* __restrict__ loss_acc,
               float* __restrict__ qout, float* __restrict__ tokmap) {
    const int t = threadIdx.x;
    const int n = blockIdx.x * 256 + t;
    const int b = n >> 10;
    const int p = n & 1023;

    const float d0 = pmin[n];
    const float d1 = pmin[N_TOT + n];
    const int i0 = pidx[n];
    const int i1 = pidx[N_TOT + n];
    const int idx = (d1 < d0) ? i1 : i0;   // tie -> lower half (lower k)

    tokmap[n] = (float)idx;
    atomicAdd(&counts[idx], 1.0f);

    const float* zrow = z + (size_t)b * (C_DIM * HWN) + p;
    float* qrow = qout + (size_t)b * (C_DIM * HWN) + p;
    const float* erow = e + (size_t)idx * C_DIM;
    float* dwrow = dw + (size_t)idx * C_DIM;

    float lsum = 0.0f;
    for (int c = 0; c < C_DIM; c += 4) {
        const float4 ev = *(const float4*)(erow + c);
        const float qv[4] = {ev.x, ev.y, ev.z, ev.w};
        #pragma unroll
        for (int j = 0; j < 4; j++) {
            const float zv = zrow[(size_t)(c + j) * HWN];
            qrow[(size_t)(c + j) * HWN] = qv[j];
            const float df = qv[j] - zv;
            lsum = fmaf(df, df, lsum);
            atomicAdd(&dwrow[c + j], zv);
        }
    }
    #pragma unroll
    for (int off = 32; off > 0; off >>= 1) lsum += __shfl_down(lsum, off, 64);
    __shared__ float ls[4];
    if ((t & 63) == 0) ls[t >> 6] = lsum;
    __syncthreads();
    if (t == 0) atomicAdd(loss_acc, ls[0] + ls[1] + ls[2] + ls[3]);
}

// 1 block, 1024 threads: EMA cluster size, n_total, cluster_size, loss, perplexity.
__global__ void vq_finalize_small(const float* __restrict__ counts,
                                  const float* __restrict__ ema_cs,
                                  const float* __restrict__ loss_acc,
                                  float* __restrict__ out_loss,
                                  float* __restrict__ out_perp,
                                  float* __restrict__ out_ncs,
                                  float* __restrict__ csize) {
    __shared__ float sdata[1024];
    const int t = threadIdx.x;
    const float cnt = counts[t];
    const float ncs = ema_cs[t] * 0.99f + 0.01f * cnt;
    out_ncs[t] = ncs;

    sdata[t] = ncs;
    __syncthreads();
    for (int s = 512; s > 0; s >>= 1) {
        if (t < s) sdata[t] += sdata[t + s];
        __syncthreads();
    }
    const float n_total = sdata[0];
    __syncthreads();

    csize[t] = (ncs + 1e-10f) / (n_total + 1024.0f * 1e-10f) * n_total;

    const float pr = cnt * (1.0f / 32768.0f);
    sdata[t] = pr * logf(pr + 1e-10f);
    __syncthreads();
    for (int s = 512; s > 0; s >>= 1) {
        if (t < s) sdata[t] += sdata[t + s];
        __syncthreads();
    }
    if (t == 0) {
        out_perp[0] = expf(-sdata[0]);
        out_loss[0] = 0.25f * loss_acc[0] * (1.0f / (float)NELEM);
    }
}

// grid 256 x 256 threads, float4 each: new_ema_w and new_embedding.
__global__ __launch_bounds__(256)
void vq_finalize_big(const float* __restrict__ ema_w, const float* __restrict__ dw,
                     const float* __restrict__ csize,
                     float* __restrict__ out_ema_w, float* __restrict__ out_emb) {
    const int i4 = blockIdx.x * 256 + threadIdx.x;   // float4 index
    const int k = i4 >> 6;                           // 64 float4 per row of 256
    const float4 w = ((const float4*)ema_w)[i4];
    const float4 d = ((const float4*)dw)[i4];
    float4 nw;
    nw.x = fmaf(w.x, 0.99f, 0.01f * d.x);
    nw.y = fmaf(w.y, 0.99f, 0.01f * d.y);
    nw.z = fmaf(w.z, 0.99f, 0.01f * d.z);
    nw.w = fmaf(w.w, 0.99f, 0.01f * d.w);
    ((float4*)out_ema_w)[i4] = nw;
    const float cs = csize[k];
    float4 ne;
    ne.x = nw.x / cs; ne.y = nw.y / cs; ne.z = nw.z / cs; ne.w = nw.w / cs;
    ((float4*)out_emb)[i4] = ne;
}

extern "C" void kernel_launch(void* const* d_in, const int* in_sizes, int n_in,
                              void* d_out, int out_size, void* d_ws, size_t ws_size,
                              hipStream_t stream) {
    const float* z      = (const float*)d_in[0];
    const float* e      = (const float*)d_in[1];
    const float* ema_cs = (const float*)d_in[2];
    const float* ema_w  = (const float*)d_in[3];
    float* out = (float*)d_out;
    float* ws  = (float*)d_ws;

    float* dw       = ws;
    float* counts   = ws + 262144;
    float* loss_acc = ws + 263168;
    float* pmin     = ws + 263424;
    int*   pidx     = (int*)(ws + 328960);
    float* enorm    = ws + 394496;
    float* csize    = ws + 395520;

    // zero dw + counts + loss_acc (contiguous)
    hipMemsetAsync(ws, 0, (size_t)263169 * sizeof(float), stream);

    vq_enorm<<<256, 256, 0, stream>>>(e, enorm);
    vq_argmin<<<dim3(256, 2), 256, 0, stream>>>(z, e, enorm, pmin, pidx);
    vq_gather<<<128, 256, 0, stream>>>(z, e, pmin, pidx, counts, dw, loss_acc,
                                       out /*q*/, out + 8388610 /*token_map*/);
    vq_finalize_small<<<1, 1024, 0, stream>>>(counts, ema_cs, loss_acc,
                                              out + 8388608, out + 8388609,
                                              out + 8421378, csize);
    vq_finalize_big<<<256, 256, 0, stream>>>(ema_w, dw, csize,
                                             out + 8422402, out + 8684546);
}

// Round 2
// 593.632 us; speedup vs baseline: 3.0194x; 3.0194x over previous
//
#include <hip/hip_runtime.h>

// Problem constants
#define K_CODES 1024
#define C_DIM   256
#define HWN     1024      // H*W
#define N_TOT   32768     // B*H*W
#define NELEM   8388608   // B*C*H*W
#define CHW     (C_DIM*HWN)
#define BIGF    3.4e38f

// ---------------- ws layout (in floats) ----------------
// pmin      : [0,      65536)
// pidx(int) : [65536,  131072)
// enorm     : [131072, 132096)
// csize     : [132096, 133120)
// counts_i  : [133120, 134144)  (int)
// loss_acc  : [134144, 134145)  -- memset covers counts_i..loss_acc (4100 B)
// base(int) : [134160, 135184)
// offs(int) : [135184, 136208)
// idx_arr   : [136208, 168976)  (int)
// order     : [168976, 201744)  (int)
// dw        : [201744, 463888)
// zt        : [463888, 463888+8388608)   (only if ws_size permits)

// ---------------- d_out layout (floats) ----------------
// q_out     : 0          (8388608)
// loss      : 8388608
// perplexity: 8388609
// token_map : 8388610    (32768, as float)
// new_cs    : 8421378    (1024)
// new_ema_w : 8422402    (262144)
// new_emb   : 8684546    (262144)

__global__ void vq_enorm(const float* __restrict__ e, float* __restrict__ enorm) {
    const int t = threadIdx.x;
    const int w = t >> 6;
    const int lane = t & 63;
    const int k = blockIdx.x * 4 + w;
    const float4 v = *(const float4*)(e + (size_t)k * C_DIM + lane * 4);
    float s = fmaf(v.x, v.x, fmaf(v.y, v.y, fmaf(v.z, v.z, v.w * v.w)));
    #pragma unroll
    for (int off = 32; off > 0; off >>= 1) s += __shfl_down(s, off, 64);
    if (lane == 0) enorm[k] = s;
}

// Fused distance-GEMM + argmin. grid (256 n-tiles, 2 k-halves), block 256.
__global__ __launch_bounds__(256, 2)
void vq_argmin(const float* __restrict__ z, const float* __restrict__ e,
               const float* __restrict__ enorm,
               float* __restrict__ pmin, int* __restrict__ pidx) {
    __shared__ float es[8][132];
    __shared__ float red_d[16][16][8];
    __shared__ int   red_i[16][16][8];

    const int tid = threadIdx.x;
    const int tx = tid & 15;
    const int ty = tid >> 4;
    const int n0 = blockIdx.x * 128;
    const int ksplit = blockIdx.y;
    const int b = n0 >> 10;
    const int p0 = n0 & 1023;
    const float* zb = z + (size_t)b * CHW + p0;

    const int kk = tid >> 1;
    const int c4 = (tid & 1) * 4;
    const int phys = kk ^ (((kk >> 5) & 3) << 2);

    const int sw = ((tx >> 2) & 3) << 2;
    const int pA = (tx * 8) ^ sw;
    const int pB = (tx * 8 + 4) ^ sw;

    float bestd[8];
    int   besti[8];
    #pragma unroll
    for (int i = 0; i < 8; i++) { bestd[i] = BIGF; besti[i] = 0; }

    for (int ks = 0; ks < 4; ++ks) {
        const int kb = ksplit * 512 + ks * 128;
        float acc[8][8];
        #pragma unroll
        for (int i = 0; i < 8; i++)
            #pragma unroll
            for (int j = 0; j < 8; j++) acc[i][j] = 0.0f;

        for (int cb = 0; cb < C_DIM; cb += 8) {
            __syncthreads();
            const float4 ev = *(const float4*)(e + (size_t)(kb + kk) * C_DIM + cb + c4);
            es[c4 + 0][phys] = ev.x;
            es[c4 + 1][phys] = ev.y;
            es[c4 + 2][phys] = ev.z;
            es[c4 + 3][phys] = ev.w;
            __syncthreads();
            #pragma unroll
            for (int c = 0; c < 8; c++) {
                const float* zc = zb + (size_t)(cb + c) * HWN + ty * 8;
                const float4 z0 = *(const float4*)(zc);
                const float4 z1 = *(const float4*)(zc + 4);
                const float4 e0 = *(const float4*)&es[c][pA];
                const float4 e1 = *(const float4*)&es[c][pB];
                const float zr[8] = {z0.x, z0.y, z0.z, z0.w, z1.x, z1.y, z1.z, z1.w};
                const float er[8] = {e0.x, e0.y, e0.z, e0.w, e1.x, e1.y, e1.z, e1.w};
                #pragma unroll
                for (int i = 0; i < 8; i++)
                    #pragma unroll
                    for (int j = 0; j < 8; j++)
                        acc[i][j] = fmaf(zr[i], er[j], acc[i][j]);
            }
        }
        #pragma unroll
        for (int j = 0; j < 8; j++) {
            const int kidx = kb + tx * 8 + j;
            const float en = enorm[kidx];
            #pragma unroll
            for (int i = 0; i < 8; i++) {
                const float d = fmaf(-2.0f, acc[i][j], en);
                if (d < bestd[i]) { bestd[i] = d; besti[i] = kidx; }
            }
        }
    }

    __syncthreads();
    #pragma unroll
    for (int i = 0; i < 8; i++) { red_d[ty][tx][i] = bestd[i]; red_i[ty][tx][i] = besti[i]; }
    __syncthreads();
    if (tid < 128) {
        const int tyr = tid >> 3, ir = tid & 7;
        float bd = BIGF; int bi = 0;
        for (int t = 0; t < 16; t++) {
            const float d = red_d[tyr][t][ir];
            if (d < bd) { bd = d; bi = red_i[tyr][t][ir]; }
        }
        const int n = n0 + tid;
        pmin[(size_t)ksplit * N_TOT + n] = bd;
        pidx[(size_t)ksplit * N_TOT + n] = bi;
    }
}

// Combine halves, token_map, counts, idx_arr, q_out, loss, transposed z copy.
// grid (128 n-blocks, 4 c-splits) x 256 threads.
__global__ __launch_bounds__(256)
void vq_combine(const float* __restrict__ z, const float* __restrict__ e,
                const float* __restrict__ pmin, const int* __restrict__ pidx,
                int* __restrict__ counts_i, int* __restrict__ idx_arr,
                float* __restrict__ loss_acc,
                float* __restrict__ qout, float* __restrict__ tokmap,
                float* __restrict__ zt, const int use_zt) {
    const int t = threadIdx.x;
    const int n = blockIdx.x * 256 + t;
    const int csplit = blockIdx.y;         // covers c in [csplit*64, csplit*64+64)
    const int b = n >> 10;
    const int p = n & 1023;

    const float d0 = pmin[n];
    const float d1 = pmin[N_TOT + n];
    const int idx = (d1 < d0) ? pidx[N_TOT + n] : pidx[n];

    if (csplit == 0) {
        tokmap[n] = (float)idx;
        idx_arr[n] = idx;
        atomicAdd(&counts_i[idx], 1);
    }

    const float* zrow = z + (size_t)b * CHW + p;
    float* qrow = qout + (size_t)b * CHW + p;
    const float* erow = e + (size_t)idx * C_DIM;

    float lsum = 0.0f;
    for (int cc = 0; cc < 64; cc += 16) {
        const int cb = csplit * 64 + cc;
        float ev[16];
        #pragma unroll
        for (int q4 = 0; q4 < 4; q4++) {
            const float4 v = *(const float4*)(erow + cb + q4 * 4);
            ev[q4*4+0] = v.x; ev[q4*4+1] = v.y; ev[q4*4+2] = v.z; ev[q4*4+3] = v.w;
        }
        float zv[16];
        #pragma unroll
        for (int j = 0; j < 16; j++) {
            zv[j] = zrow[(size_t)(cb + j) * HWN];
            qrow[(size_t)(cb + j) * HWN] = ev[j];
            const float df = ev[j] - zv[j];
            lsum = fmaf(df, df, lsum);
        }
        if (use_zt) {
            // thread already holds its point's 16 channels -> contiguous store
            #pragma unroll
            for (int q4 = 0; q4 < 4; q4++) {
                float4 o;
                o.x = zv[q4*4+0]; o.y = zv[q4*4+1]; o.z = zv[q4*4+2]; o.w = zv[q4*4+3];
                *(float4*)(zt + (size_t)n * C_DIM + cb + q4 * 4) = o;
            }
        }
    }
    #pragma unroll
    for (int off = 32; off > 0; off >>= 1) lsum += __shfl_down(lsum, off, 64);
    __shared__ float ls[4];
    if ((t & 63) == 0) ls[t >> 6] = lsum;
    __syncthreads();
    if (t == 0) atomicAdd(loss_acc, ls[0] + ls[1] + ls[2] + ls[3]);
}

// 1 block, 1024 threads: EMA cluster size, cluster_size, loss, perplexity,
// and exclusive prefix sum of counts -> base/offs.
__global__ void vq_scan_small(const int* __restrict__ counts_i,
                              const float* __restrict__ ema_cs,
                              const float* __restrict__ loss_acc,
                              float* __restrict__ out_loss,
                              float* __restrict__ out_perp,
                              float* __restrict__ out_ncs,
                              float* __restrict__ csize,
                              int* __restrict__ base, int* __restrict__ offs) {
    __shared__ float sf[1024];
    __shared__ int si[1024];
    const int t = threadIdx.x;
    const int ci = counts_i[t];
    const float cnt = (float)ci;
    const float ncs = ema_cs[t] * 0.99f + 0.01f * cnt;
    out_ncs[t] = ncs;

    sf[t] = ncs;
    __syncthreads();
    for (int s = 512; s > 0; s >>= 1) { if (t < s) sf[t] += sf[t + s]; __syncthreads(); }
    const float n_total = sf[0];
    __syncthreads();

    csize[t] = (ncs + 1e-10f) / (n_total + 1024.0f * 1e-10f) * n_total;

    const float pr = cnt * (1.0f / 32768.0f);
    sf[t] = pr * logf(pr + 1e-10f);
    __syncthreads();
    for (int s = 512; s > 0; s >>= 1) { if (t < s) sf[t] += sf[t + s]; __syncthreads(); }
    if (t == 0) {
        out_perp[0] = expf(-sf[0]);
        out_loss[0] = 0.25f * loss_acc[0] * (1.0f / (float)NELEM);
    }

    // Hillis-Steele inclusive scan of counts
    si[t] = ci;
    __syncthreads();
    for (int d = 1; d < 1024; d <<= 1) {
        const int x = si[t];
        const int y = (t >= d) ? si[t - d] : 0;
        __syncthreads();
        si[t] = x + y;
        __syncthreads();
    }
    const int excl = si[t] - ci;
    base[t] = excl;
    offs[t] = excl;
}

// scatter point ids into per-code contiguous lists
__global__ __launch_bounds__(256)
void vq_scatter(const int* __restrict__ idx_arr, int* __restrict__ offs,
                int* __restrict__ order) {
    const int n = blockIdx.x * 256 + threadIdx.x;
    const int idx = idx_arr[n];
    const int pos = atomicAdd(&offs[idx], 1);
    order[pos] = n;
}

// one block per code: dw[k][c] = sum of zt rows; coalesced, no atomics
__global__ __launch_bounds__(256)
void vq_dw_zt(const float* __restrict__ zt, const int* __restrict__ order,
              const int* __restrict__ base, const int* __restrict__ counts_i,
              float* __restrict__ dw) {
    const int k = blockIdx.x;
    const int t = threadIdx.x;
    const int start = base[k];
    const int cnt = counts_i[k];
    float acc = 0.0f;
    int i = 0;
    for (; i + 1 < cnt; i += 2) {
        const int n0 = order[start + i];
        const int n1 = order[start + i + 1];
        const float a = zt[(size_t)n0 * C_DIM + t];
        const float c = zt[(size_t)n1 * C_DIM + t];
        acc += a; acc += c;
    }
    if (i < cnt) acc += zt[(size_t)order[start + i] * C_DIM + t];
    dw[(size_t)k * C_DIM + t] = acc;
}

// fallback when ws too small for zt: read original strided layout
__global__ __launch_bounds__(256)
void vq_dw_strided(const float* __restrict__ z, const int* __restrict__ order,
                   const int* __restrict__ base, const int* __restrict__ counts_i,
                   float* __restrict__ dw) {
    const int k = blockIdx.x;
    const int t = threadIdx.x;   // channel
    const int start = base[k];
    const int cnt = counts_i[k];
    float acc = 0.0f;
    for (int i = 0; i < cnt; i++) {
        const int n = order[start + i];
        const int b = n >> 10;
        const int p = n & 1023;
        acc += z[(size_t)b * CHW + (size_t)t * HWN + p];
    }
    dw[(size_t)k * C_DIM + t] = acc;
}

__global__ __launch_bounds__(256)
void vq_finalize_big(const float* __restrict__ ema_w, const float* __restrict__ dw,
                     const float* __restrict__ csize,
                     float* __restrict__ out_ema_w, float* __restrict__ out_emb) {
    const int i4 = blockIdx.x * 256 + threadIdx.x;
    const int k = i4 >> 6;
    const float4 w = ((const float4*)ema_w)[i4];
    const float4 d = ((const float4*)dw)[i4];
    float4 nw;
    nw.x = fmaf(w.x, 0.99f, 0.01f * d.x);
    nw.y = fmaf(w.y, 0.99f, 0.01f * d.y);
    nw.z = fmaf(w.z, 0.99f, 0.01f * d.z);
    nw.w = fmaf(w.w, 0.99f, 0.01f * d.w);
    ((float4*)out_ema_w)[i4] = nw;
    const float cs = csize[k];
    float4 ne;
    ne.x = nw.x / cs; ne.y = nw.y / cs; ne.z = nw.z / cs; ne.w = nw.w / cs;
    ((float4*)out_emb)[i4] = ne;
}

extern "C" void kernel_launch(void* const* d_in, const int* in_sizes, int n_in,
                              void* d_out, int out_size, void* d_ws, size_t ws_size,
                              hipStream_t stream) {
    const float* z      = (const float*)d_in[0];
    const float* e      = (const float*)d_in[1];
    const float* ema_cs = (const float*)d_in[2];
    const float* ema_w  = (const float*)d_in[3];
    float* out = (float*)d_out;
    float* ws  = (float*)d_ws;

    float* pmin     = ws;
    int*   pidx     = (int*)(ws + 65536);
    float* enorm    = ws + 131072;
    float* csize    = ws + 132096;
    int*   counts_i = (int*)(ws + 133120);
    float* loss_acc = ws + 134144;
    int*   base     = (int*)(ws + 134160);
    int*   offs     = (int*)(ws + 135184);
    int*   idx_arr  = (int*)(ws + 136208);
    int*   order    = (int*)(ws + 168976);
    float* dw       = ws + 201744;
    float* zt       = ws + 463888;

    const size_t need_zt = (size_t)(463888 + 8388608) * sizeof(float);
    const int use_zt = (ws_size >= need_zt) ? 1 : 0;

    // zero counts_i + loss_acc (contiguous 1025 words)
    hipMemsetAsync(ws + 133120, 0, 4100, stream);

    vq_enorm<<<256, 256, 0, stream>>>(e, enorm);
    vq_argmin<<<dim3(256, 2), 256, 0, stream>>>(z, e, enorm, pmin, pidx);
    vq_combine<<<dim3(128, 4), 256, 0, stream>>>(z, e, pmin, pidx, counts_i,
                                                 idx_arr, loss_acc,
                                                 out, out + 8388610, zt, use_zt);
    vq_scan_small<<<1, 1024, 0, stream>>>(counts_i, ema_cs, loss_acc,
                                          out + 8388608, out + 8388609,
                                          out + 8421378, csize, base, offs);
    vq_scatter<<<128, 256, 0, stream>>>(idx_arr, offs, order);
    if (use_zt)
        vq_dw_zt<<<1024, 256, 0, stream>>>(zt, order, base, counts_i, dw);
    else
        vq_dw_strided<<<1024, 256, 0, stream>>>(z, order, base, counts_i, dw);
    vq_finalize_big<<<256, 256, 0, stream>>>(ema_w, dw, csize,
                                             out + 8422402, out + 8684546);
}